// Round 1
// baseline (97.684 us; speedup 1.0000x reference)
//
#include <hip/hip_runtime.h>

// SKAttention fused kernel, MI355X.
// Shapes: x,x1 (128, 512, 16, 16) f32; fc_w (32,512); fc_b (32);
// fcs_w (2,512,32); fcs_b (2,512). Outputs: 2 x (128, 512, 12, 16) f32, concat flat.
//
// Structure insight: softmax is over the 2-branch axis only -> attn0 = sigmoid(l0-l1).
// _cat drops patch group 0, and patch p's attention depends only on patch p,
// so image rows 0..3 are dead. Only rows 4..15 are read.
//
// Block = (group g in {1,2,3}, batch b). 384 blocks x 512 threads.
//  Phase 1: patch means of (x+x1) for the 4 patches of this group -> LDS
//  Phase 2a: Z[j][d] = mean . fc_w  (128 threads, 4x32 outputs)
//  Phase 2b: attn0[ch][j] = sigmoid( Z[j] . (fcs_w0[ch]-fcs_w1[ch]) + b0-b1 )
//  Phase 3: out1 = attn0 * x + x_diag ; out2 = (1-attn0) * x1 + x1_diag
//           (x/x1 re-read hits L2/L3; diag slice is 128 KB per g, L2-resident)

#define BS 128
#define C  512
#define D  32

__global__ __launch_bounds__(512) void skatt_fused(
    const float* __restrict__ x,
    const float* __restrict__ x1,
    const float* __restrict__ fc_w,   // (32, 512)
    const float* __restrict__ fc_b,   // (32,)
    const float* __restrict__ fcs_w,  // (2, 512, 32)
    const float* __restrict__ fcs_b,  // (2, 512)
    float* __restrict__ out)          // out1 | out2, each (128,512,12,16)
{
    const int g = blockIdx.x + 1;     // group 1..3
    const int b = blockIdx.y;         // batch 0..127
    const int t = threadIdx.x;        // 0..511

    __shared__ float s_mean[4][C];    // [j][ch] mean of (x+x1) patch
    __shared__ float s_z[4][D];       // [j][d]
    __shared__ float s_attn[C][4];    // [ch][j] attn0 (branch 0 weight)

    const float* xb  = x  + (size_t)b * (C * 256) + g * 64;   // row 4g of batch b
    const float* x1b = x1 + (size_t)b * (C * 256) + g * 64;

    // ---- Phase 1: per-patch means of (x + x1) ----
    {
        const int j   = t & 3;
        const int chb = t >> 2;              // 0..127
        #pragma unroll
        for (int it = 0; it < 4; ++it) {
            const int ch = chb + 128 * it;
            const float* px = xb  + ch * 256 + j * 4;
            const float* p1 = x1b + ch * 256 + j * 4;
            float s = 0.f;
            #pragma unroll
            for (int h = 0; h < 4; ++h) {
                float4 a = *(const float4*)(px + h * 16);
                float4 c2 = *(const float4*)(p1 + h * 16);
                s += (a.x + c2.x) + (a.y + c2.y) + (a.z + c2.z) + (a.w + c2.w);
            }
            s_mean[j][ch] = s * (1.0f / 16.0f);
        }
    }
    __syncthreads();

    // ---- Phase 2a: Z[j][d] = sum_c s_mean[j][c] * fc_w[d][c] + fc_b[d] ----
    if (t < 128) {
        const int j = t >> 5;
        const int d = t & 31;
        const float4* wrow = (const float4*)(fc_w + d * C);
        const float4* srow = (const float4*)(&s_mean[j][0]);
        float acc = 0.f;
        #pragma unroll 4
        for (int c4 = 0; c4 < C / 4; ++c4) {
            float4 w = wrow[c4];
            float4 s = srow[c4];
            acc += w.x * s.x + w.y * s.y + w.z * s.z + w.w * s.w;
        }
        s_z[j][d] = acc + fc_b[d];
    }
    __syncthreads();

    // ---- Phase 2b: attn0[ch][j] = sigmoid(ldiff) ----
    {
        #pragma unroll
        for (int it = 0; it < 4; ++it) {
            const int idx = t + it * 512;     // 0..2047
            const int j  = idx >> 9;
            const int ch = idx & 511;
            const float4* w0 = (const float4*)(fcs_w + ch * D);
            const float4* w1 = (const float4*)(fcs_w + C * D + ch * D);
            const float4* zz = (const float4*)(&s_z[j][0]);
            float acc = fcs_b[ch] - fcs_b[C + ch];
            #pragma unroll
            for (int d4 = 0; d4 < D / 4; ++d4) {
                float4 a = w0[d4], c2 = w1[d4], z = zz[d4];
                acc += z.x * (a.x - c2.x) + z.y * (a.y - c2.y)
                     + z.z * (a.z - c2.z) + z.w * (a.w - c2.w);
            }
            s_attn[ch][j] = 1.0f / (1.0f + __expf(-acc));
        }
    }
    __syncthreads();

    // ---- Phase 3: outputs ----
    // out1[b,ch,(g-1)*4+h, 4j+w] = attn0 * x[b,ch,4g+h,4j+w] + x[4g+j,ch,4g+h,4j+w]
    // out2 same with x1 and (1-attn0).
    const size_t out2_off = (size_t)BS * C * 192;
    float* o1 = out + (size_t)b * (C * 192) + (g - 1) * 64;
    float* o2 = o1 + out2_off;

    #pragma unroll 4
    for (int it = 0; it < 16; ++it) {
        const int f  = t + it * 512;     // 0..8191
        const int ch = f >> 4;
        const int h  = (f >> 2) & 3;
        const int j  = f & 3;
        const int ofs = ch * 256 + h * 16 + j * 4;

        float4 a  = *(const float4*)(xb  + ofs);
        float4 c2 = *(const float4*)(x1b + ofs);

        // diagonal extras: batch 4g+j, same spatial location
        const size_t dofs = (size_t)(4 * g + j) * (C * 256) + ch * 256 + g * 64 + h * 16 + j * 4;
        float4 dg  = *(const float4*)(x  + dofs);
        float4 dg2 = *(const float4*)(x1 + dofs);

        const float at0 = s_attn[ch][j];
        const float at1 = 1.0f - at0;

        float4 r1, r2;
        r1.x = at0 * a.x + dg.x;   r2.x = at1 * c2.x + dg2.x;
        r1.y = at0 * a.y + dg.y;   r2.y = at1 * c2.y + dg2.y;
        r1.z = at0 * a.z + dg.z;   r2.z = at1 * c2.z + dg2.z;
        r1.w = at0 * a.w + dg.w;   r2.w = at1 * c2.w + dg2.w;

        const int oofs = ch * 192 + h * 16 + j * 4;
        *(float4*)(o1 + oofs) = r1;
        *(float4*)(o2 + oofs) = r2;
    }
}

extern "C" void kernel_launch(void* const* d_in, const int* in_sizes, int n_in,
                              void* d_out, int out_size, void* d_ws, size_t ws_size,
                              hipStream_t stream) {
    const float* x     = (const float*)d_in[0];
    const float* x1    = (const float*)d_in[1];
    const float* fc_w  = (const float*)d_in[2];
    const float* fc_b  = (const float*)d_in[3];
    const float* fcs_w = (const float*)d_in[4];
    const float* fcs_b = (const float*)d_in[5];
    float* out = (float*)d_out;

    dim3 grid(3, BS);
    skatt_fused<<<grid, 512, 0, stream>>>(x, x1, fc_w, fc_b, fcs_w, fcs_b, out);
}